// Round 1
// baseline (319.626 us; speedup 1.0000x reference)
//
#include <hip/hip_runtime.h>

// Problem: B=4096, N=50, D=128, R=3, K=128, 2D=256, RD=768
// out[b,n] = sum_d ao_in[b,n,d] * v[b, s[b,n], d]
//   v[b,r,d] = sum_{d'} ui_in[b,d'] * M[r,d,d'] + c[r,d]
//   M[r,d,d'] = sum_k w_aor[r,d,k] * w_uir[r,d',k]
//   c[r,d]    = sum_k w_aor[r,d,k] * r_param[r,k]
//
// ws layout (floats):
//   v    : [4096][768]   at offset 0            (12,582,912 B)
//   w2t  : [768][256]    at 4096*768            (786,432 B)   row rd=r*256+d, col d'
//   cvec : [768]         after w2t              (3,072 B)

#define TWO_D 256
#define RD 768

// ---------------- Kernel A: M + c precompute (GEMM 256x256x128 per r) --------
__global__ __launch_bounds__(256) void relproj_kernel(
    const float* __restrict__ w_aor, const float* __restrict__ w_uir,
    const float* __restrict__ r_param, float* __restrict__ w2t,
    float* __restrict__ cvec)
{
    const int r  = blockIdx.z;
    const int d0 = blockIdx.x * 64;   // m-dim: d   (rows of w_aor[r])
    const int p0 = blockIdx.y * 64;   // n-dim: d'  (rows of w_uir[r])
    const int tid = threadIdx.x;
    const int tx = tid & 15, ty = tid >> 4;

    __shared__ float4 a4[64][16];
    __shared__ float4 b4[64][16];

    float acc[4][4];
#pragma unroll
    for (int i = 0; i < 4; ++i)
#pragma unroll
        for (int j = 0; j < 4; ++j) acc[i][j] = 0.f;

    const float* Am = w_aor + (size_t)r * 256 * 128;
    const float* Bm = w_uir + (size_t)r * 256 * 128;

    for (int ks = 0; ks < 2; ++ks) {
        const int kb = ks * 64;
        __syncthreads();
#pragma unroll
        for (int i = 0; i < 4; ++i) {
            int f = tid + i * 256;          // [0,1024)
            int row = f >> 4, k4 = f & 15;
            int slot = k4 ^ ((row >> 2) & 15);
            a4[row][slot] = *(const float4*)(Am + (size_t)(d0 + row) * 128 + kb + k4 * 4);
            b4[row][slot] = *(const float4*)(Bm + (size_t)(p0 + row) * 128 + kb + k4 * 4);
        }
        __syncthreads();
#pragma unroll
        for (int k4 = 0; k4 < 16; ++k4) {
            float4 av[4], bv[4];
#pragma unroll
            for (int i = 0; i < 4; ++i) { int m = ty * 4 + i; av[i] = a4[m][k4 ^ ((m >> 2) & 15)]; }
#pragma unroll
            for (int j = 0; j < 4; ++j) { int n = tx * 4 + j; bv[j] = b4[n][k4 ^ ((n >> 2) & 15)]; }
#pragma unroll
            for (int i = 0; i < 4; ++i)
#pragma unroll
                for (int j = 0; j < 4; ++j)
                    acc[i][j] += av[i].x * bv[j].x + av[i].y * bv[j].y +
                                 av[i].z * bv[j].z + av[i].w * bv[j].w;
        }
    }

#pragma unroll
    for (int i = 0; i < 4; ++i) {
        int m = ty * 4 + i;                          // d index within tile
        float4 o = make_float4(acc[i][0], acc[i][1], acc[i][2], acc[i][3]);
        *(float4*)(w2t + (size_t)(r * 256 + d0 + m) * 256 + p0 + tx * 4) = o;
    }

    // bias c[r*256+d] computed by blocks with p-tile 0
    if (blockIdx.y == 0 && tid < 64) {
        int d = d0 + tid;
        const float* ar = Am + (size_t)d * 128;
        const float* rp = r_param + r * 128;
        float ssum = 0.f;
#pragma unroll 4
        for (int kk = 0; kk < 128; ++kk) ssum += ar[kk] * rp[kk];
        cvec[r * 256 + d] = ssum;
    }
}

// ---------------- Kernel B: v = ui_in @ w2t^T + c  (4096 x 768 x 256) --------
__global__ __launch_bounds__(256) void vproj_kernel(
    const float* __restrict__ u_emb, const float* __restrict__ i_emb,
    const float* __restrict__ w2t, const float* __restrict__ cvec,
    float* __restrict__ v)
{
    const int b0 = blockIdx.x * 64;   // m: batch rows
    const int n0 = blockIdx.y * 64;   // n: rd columns
    const int tid = threadIdx.x;
    const int tx = tid & 15, ty = tid >> 4;

    __shared__ float4 a4[64][16];
    __shared__ float4 b4[64][16];

    float acc[4][4];
#pragma unroll
    for (int i = 0; i < 4; ++i)
#pragma unroll
        for (int j = 0; j < 4; ++j) acc[i][j] = 0.f;

    for (int ks = 0; ks < 4; ++ks) {
        const float* src = (ks < 2) ? u_emb : i_emb;
        const int kb = (ks & 1) * 64;   // column within u/i (each 128 wide)
        __syncthreads();
#pragma unroll
        for (int i = 0; i < 4; ++i) {
            int f = tid + i * 256;
            int row = f >> 4, k4 = f & 15;
            int slot = k4 ^ ((row >> 2) & 15);
            a4[row][slot] = *(const float4*)(src + (size_t)(b0 + row) * 128 + kb + k4 * 4);
            b4[row][slot] = *(const float4*)(w2t + (size_t)(n0 + row) * 256 + ks * 64 + k4 * 4);
        }
        __syncthreads();
#pragma unroll
        for (int k4 = 0; k4 < 16; ++k4) {
            float4 av[4], bv[4];
#pragma unroll
            for (int i = 0; i < 4; ++i) { int m = ty * 4 + i; av[i] = a4[m][k4 ^ ((m >> 2) & 15)]; }
#pragma unroll
            for (int j = 0; j < 4; ++j) { int n = tx * 4 + j; bv[j] = b4[n][k4 ^ ((n >> 2) & 15)]; }
#pragma unroll
            for (int i = 0; i < 4; ++i)
#pragma unroll
                for (int j = 0; j < 4; ++j)
                    acc[i][j] += av[i].x * bv[j].x + av[i].y * bv[j].y +
                                 av[i].z * bv[j].z + av[i].w * bv[j].w;
        }
    }

    const float4 cb = *(const float4*)(cvec + n0 + tx * 4);
#pragma unroll
    for (int i = 0; i < 4; ++i) {
        int m = ty * 4 + i;
        float4 o = make_float4(acc[i][0] + cb.x, acc[i][1] + cb.y,
                               acc[i][2] + cb.z, acc[i][3] + cb.w);
        *(float4*)(v + (size_t)(b0 + m) * RD + n0 + tx * 4) = o;
    }
}

// ---------------- Kernel C: out[b,n] = dot(ao_in[b,n], v[b, s[b,n]]) ---------
__global__ __launch_bounds__(256) void score_kernel(
    const float* __restrict__ a_emb, const float* __restrict__ o_emb,
    const float* __restrict__ v, const int* __restrict__ s,
    float* __restrict__ out)
{
    const int b = blockIdx.x;
    const int tid = threadIdx.x;

    __shared__ float4 v4[192];   // 768 floats = v[b][0..767]
    __shared__ int sl[52];

    if (tid < 192) v4[tid] = ((const float4*)(v + (size_t)b * RD))[tid];
    if (tid < 50) sl[tid] = s[(size_t)b * 50 + tid];
    __syncthreads();

    const int w = tid >> 6, l = tid & 63;
    const float4* a4p = (const float4*)a_emb;
    const float4* o4p = (const float4*)o_emb;

    for (int n = w; n < 50; n += 4) {
        const int rel = sl[n];
        const size_t base4 = ((size_t)b * 50 + n) * 32;   // float4 units (128 floats/row)
        const float4* srcp = (l < 32) ? a4p : o4p;
        const int li = (l < 32) ? l : (l - 32);
        float4 x = srcp[base4 + li];
        float4 vv = v4[rel * 64 + l];
        float p = x.x * vv.x + x.y * vv.y + x.z * vv.z + x.w * vv.w;
#pragma unroll
        for (int off = 32; off >= 1; off >>= 1) p += __shfl_xor(p, off, 64);
        if (l == 0) out[(size_t)b * 50 + n] = p;
    }
}

extern "C" void kernel_launch(void* const* d_in, const int* in_sizes, int n_in,
                              void* d_out, int out_size, void* d_ws, size_t ws_size,
                              hipStream_t stream)
{
    const float* u_emb   = (const float*)d_in[0];
    const float* i_emb   = (const float*)d_in[1];
    const float* a_emb   = (const float*)d_in[2];
    const float* o_emb   = (const float*)d_in[3];
    const float* w_aor   = (const float*)d_in[4];
    const float* w_uir   = (const float*)d_in[5];
    const float* r_param = (const float*)d_in[6];
    const int*   s       = (const int*)d_in[7];
    float* out = (float*)d_out;

    float* v    = (float*)d_ws;                     // [4096][768]
    float* w2t  = v + (size_t)4096 * RD;            // [768][256]
    float* cvec = w2t + (size_t)RD * TWO_D;         // [768]

    relproj_kernel<<<dim3(4, 4, 3), 256, 0, stream>>>(w_aor, w_uir, r_param, w2t, cvec);
    vproj_kernel<<<dim3(4096 / 64, RD / 64), 256, 0, stream>>>(u_emb, i_emb, w2t, cvec, v);
    score_kernel<<<4096, 256, 0, stream>>>(a_emb, o_emb, v, s, out);
}

// Round 2
// 317.401 us; speedup vs baseline: 1.0070x; 1.0070x over previous
//
#include <hip/hip_runtime.h>

// Problem: B=4096, N=50, D=128, R=3, K=128, 2D=256, RD=768
// out[b,n] = sum_d ao_in[b,n,d] * v[b, s[b,n], d]
//   v[b,r,d] = sum_{d'} ui_in[b,d'] * M[r,d,d'] + c[r,d]
//   M[r,d,d'] = sum_k w_aor[r,d,k] * w_uir[r,d',k]
//   c[r,d]    = sum_k w_aor[r,d,k] * r_param[r,k]
//
// ws layout (floats):
//   v    : [4096][768]   at offset 0            (12,582,912 B)
//   w2t  : [768][256]    at 4096*768            (786,432 B)   row rd=r*256+d, col d'
//   cvec : [768]         after w2t              (3,072 B)

#define TWO_D 256
#define RD 768

// ---------------- Kernel A: M + c precompute (GEMM 256x256x128 per r) --------
__global__ __launch_bounds__(256) void relproj_kernel(
    const float* __restrict__ w_aor, const float* __restrict__ w_uir,
    const float* __restrict__ r_param, float* __restrict__ w2t,
    float* __restrict__ cvec)
{
    const int r  = blockIdx.z;
    const int d0 = blockIdx.x * 64;   // m-dim: d   (rows of w_aor[r])
    const int p0 = blockIdx.y * 64;   // n-dim: d'  (rows of w_uir[r])
    const int tid = threadIdx.x;
    const int tx = tid & 15, ty = tid >> 4;

    __shared__ float4 a4[64][16];
    __shared__ float4 b4[64][16];

    float acc[4][4];
#pragma unroll
    for (int i = 0; i < 4; ++i)
#pragma unroll
        for (int j = 0; j < 4; ++j) acc[i][j] = 0.f;

    const float* Am = w_aor + (size_t)r * 256 * 128;
    const float* Bm = w_uir + (size_t)r * 256 * 128;

    for (int ks = 0; ks < 2; ++ks) {
        const int kb = ks * 64;
        __syncthreads();
#pragma unroll
        for (int i = 0; i < 4; ++i) {
            int f = tid + i * 256;          // [0,1024)
            int row = f >> 4, k4 = f & 15;
            int slot = k4 ^ ((row >> 2) & 15);
            a4[row][slot] = *(const float4*)(Am + (size_t)(d0 + row) * 128 + kb + k4 * 4);
            b4[row][slot] = *(const float4*)(Bm + (size_t)(p0 + row) * 128 + kb + k4 * 4);
        }
        __syncthreads();
#pragma unroll
        for (int k4 = 0; k4 < 16; ++k4) {
            float4 av[4], bv[4];
#pragma unroll
            for (int i = 0; i < 4; ++i) { int m = ty * 4 + i; av[i] = a4[m][k4 ^ ((m >> 2) & 15)]; }
#pragma unroll
            for (int j = 0; j < 4; ++j) { int n = tx * 4 + j; bv[j] = b4[n][k4 ^ ((n >> 2) & 15)]; }
#pragma unroll
            for (int i = 0; i < 4; ++i)
#pragma unroll
                for (int j = 0; j < 4; ++j)
                    acc[i][j] += av[i].x * bv[j].x + av[i].y * bv[j].y +
                                 av[i].z * bv[j].z + av[i].w * bv[j].w;
        }
    }

#pragma unroll
    for (int i = 0; i < 4; ++i) {
        int m = ty * 4 + i;                          // d index within tile
        float4 o = make_float4(acc[i][0], acc[i][1], acc[i][2], acc[i][3]);
        *(float4*)(w2t + (size_t)(r * 256 + d0 + m) * 256 + p0 + tx * 4) = o;
    }

    // bias c[r*256+d] computed by blocks with p-tile 0
    if (blockIdx.y == 0 && tid < 64) {
        int d = d0 + tid;
        const float* ar = Am + (size_t)d * 128;
        const float* rp = r_param + r * 128;
        float ssum = 0.f;
#pragma unroll 4
        for (int kk = 0; kk < 128; ++kk) ssum += ar[kk] * rp[kk];
        cvec[r * 256 + d] = ssum;
    }
}

// ---------------- Kernel B: v = ui_in @ w2t^T + c  (4096 x 768 x 256) --------
__global__ __launch_bounds__(256) void vproj_kernel(
    const float* __restrict__ u_emb, const float* __restrict__ i_emb,
    const float* __restrict__ w2t, const float* __restrict__ cvec,
    float* __restrict__ v)
{
    const int b0 = blockIdx.x * 64;   // m: batch rows
    const int n0 = blockIdx.y * 64;   // n: rd columns
    const int tid = threadIdx.x;
    const int tx = tid & 15, ty = tid >> 4;

    __shared__ float4 a4[64][16];
    __shared__ float4 b4[64][16];

    float acc[4][4];
#pragma unroll
    for (int i = 0; i < 4; ++i)
#pragma unroll
        for (int j = 0; j < 4; ++j) acc[i][j] = 0.f;

    for (int ks = 0; ks < 4; ++ks) {
        const float* src = (ks < 2) ? u_emb : i_emb;
        const int kb = (ks & 1) * 64;   // column within u/i (each 128 wide)
        __syncthreads();
#pragma unroll
        for (int i = 0; i < 4; ++i) {
            int f = tid + i * 256;
            int row = f >> 4, k4 = f & 15;
            int slot = k4 ^ ((row >> 2) & 15);
            a4[row][slot] = *(const float4*)(src + (size_t)(b0 + row) * 128 + kb + k4 * 4);
            b4[row][slot] = *(const float4*)(w2t + (size_t)(n0 + row) * 256 + ks * 64 + k4 * 4);
        }
        __syncthreads();
#pragma unroll
        for (int k4 = 0; k4 < 16; ++k4) {
            float4 av[4], bv[4];
#pragma unroll
            for (int i = 0; i < 4; ++i) { int m = ty * 4 + i; av[i] = a4[m][k4 ^ ((m >> 2) & 15)]; }
#pragma unroll
            for (int j = 0; j < 4; ++j) { int n = tx * 4 + j; bv[j] = b4[n][k4 ^ ((n >> 2) & 15)]; }
#pragma unroll
            for (int i = 0; i < 4; ++i)
#pragma unroll
                for (int j = 0; j < 4; ++j)
                    acc[i][j] += av[i].x * bv[j].x + av[i].y * bv[j].y +
                                 av[i].z * bv[j].z + av[i].w * bv[j].w;
        }
    }

    const float4 cb = *(const float4*)(cvec + n0 + tx * 4);
#pragma unroll
    for (int i = 0; i < 4; ++i) {
        int m = ty * 4 + i;
        float4 o = make_float4(acc[i][0] + cb.x, acc[i][1] + cb.y,
                               acc[i][2] + cb.z, acc[i][3] + cb.w);
        *(float4*)(v + (size_t)(b0 + m) * RD + n0 + tx * 4) = o;
    }
}

// ---------------- Kernel C: out[b,n] = dot(ao_in[b,n], v[b, s[b,n]]) ---------
// ILP-4 version: each wave owns a contiguous slice of rows; 4 independent
// row-loads in flight + 4 interleaved shuffle-reduce chains.
__global__ __launch_bounds__(256) void score_kernel(
    const float* __restrict__ a_emb, const float* __restrict__ o_emb,
    const float* __restrict__ v, const int* __restrict__ s,
    float* __restrict__ out)
{
    const int b = blockIdx.x;
    const int tid = threadIdx.x;

    __shared__ float4 v4[192];   // 768 floats = v[b][0..767]
    __shared__ int sl[52];

    if (tid < 192) v4[tid] = ((const float4*)(v + (size_t)b * RD))[tid];
    if (tid < 50) sl[tid] = s[(size_t)b * 50 + tid];
    __syncthreads();

    const int w = tid >> 6, l = tid & 63;
    const int li = l & 31;
    const float4* srcp = (l < 32) ? (const float4*)a_emb : (const float4*)o_emb;

    const size_t rowbase = (size_t)b * 50;
    const int start = (w < 3) ? w * 13 : 39;
    const int cnt   = (w < 3) ? 13 : 11;

    // per-lane base pointer for this wave's contiguous row slice
    const float4* rp = srcp + (rowbase + start) * 32 + li;

    int i = 0;
    for (; i + 4 <= cnt; i += 4) {
        const int n0 = start + i;
        // issue 4 independent global loads (4 KB in flight per wave)
        float4 x0 = rp[(i + 0) * 32];
        float4 x1 = rp[(i + 1) * 32];
        float4 x2 = rp[(i + 2) * 32];
        float4 x3 = rp[(i + 3) * 32];
        // 4 LDS v-row loads
        float4 v0 = v4[sl[n0 + 0] * 64 + l];
        float4 v1 = v4[sl[n0 + 1] * 64 + l];
        float4 v2 = v4[sl[n0 + 2] * 64 + l];
        float4 v3 = v4[sl[n0 + 3] * 64 + l];

        float p0 = x0.x * v0.x + x0.y * v0.y + x0.z * v0.z + x0.w * v0.w;
        float p1 = x1.x * v1.x + x1.y * v1.y + x1.z * v1.z + x1.w * v1.w;
        float p2 = x2.x * v2.x + x2.y * v2.y + x2.z * v2.z + x2.w * v2.w;
        float p3 = x3.x * v3.x + x3.y * v3.y + x3.z * v3.z + x3.w * v3.w;

#pragma unroll
        for (int off = 32; off >= 1; off >>= 1) {
            p0 += __shfl_xor(p0, off, 64);
            p1 += __shfl_xor(p1, off, 64);
            p2 += __shfl_xor(p2, off, 64);
            p3 += __shfl_xor(p3, off, 64);
        }
        if (l == 0) {
            out[rowbase + n0 + 0] = p0;
            out[rowbase + n0 + 1] = p1;
            out[rowbase + n0 + 2] = p2;
            out[rowbase + n0 + 3] = p3;
        }
    }
    for (; i < cnt; ++i) {
        const int n = start + i;
        float4 x = rp[i * 32];
        float4 vv = v4[sl[n] * 64 + l];
        float p = x.x * vv.x + x.y * vv.y + x.z * vv.z + x.w * vv.w;
#pragma unroll
        for (int off = 32; off >= 1; off >>= 1) p += __shfl_xor(p, off, 64);
        if (l == 0) out[rowbase + n] = p;
    }
}

extern "C" void kernel_launch(void* const* d_in, const int* in_sizes, int n_in,
                              void* d_out, int out_size, void* d_ws, size_t ws_size,
                              hipStream_t stream)
{
    const float* u_emb   = (const float*)d_in[0];
    const float* i_emb   = (const float*)d_in[1];
    const float* a_emb   = (const float*)d_in[2];
    const float* o_emb   = (const float*)d_in[3];
    const float* w_aor   = (const float*)d_in[4];
    const float* w_uir   = (const float*)d_in[5];
    const float* r_param = (const float*)d_in[6];
    const int*   s       = (const int*)d_in[7];
    float* out = (float*)d_out;

    float* v    = (float*)d_ws;                     // [4096][768]
    float* w2t  = v + (size_t)4096 * RD;            // [768][256]
    float* cvec = w2t + (size_t)RD * TWO_D;         // [768]

    relproj_kernel<<<dim3(4, 4, 3), 256, 0, stream>>>(w_aor, w_uir, r_param, w2t, cvec);
    vproj_kernel<<<dim3(4096 / 64, RD / 64), 256, 0, stream>>>(u_emb, i_emb, w2t, cvec, v);
    score_kernel<<<4096, 256, 0, stream>>>(a_emb, o_emb, v, s, out);
}